// Round 5
// baseline (248.442 us; speedup 1.0000x reference)
//
#include <hip/hip_runtime.h>

#define BB 64
#define HH 128
#define CC 1024
#define QQ 128

typedef unsigned short u16;
typedef unsigned int u32;
using bf16x8 = __attribute__((ext_vector_type(8))) short;
using f32x4 = __attribute__((ext_vector_type(4))) float;

#define MFMA16(a, b, c) __builtin_amdgcn_mfma_f32_16x16x32_bf16(a, b, c, 0, 0, 0)

__device__ __forceinline__ u16 f2b(float f) {
  union { float f; u32 i; } v; v.f = f;
  u32 r = v.i + 0x7FFFu + ((v.i >> 16) & 1u);   // RNE
  return (u16)(r >> 16);
}
// Dekker hi/lo split packers: x = hi + lo + eps, |eps| <= 2^-17 |x|
__device__ __forceinline__ u32 pack_hi2(float a, float b) {
  return (__float_as_uint(a) >> 16) | (__float_as_uint(b) & 0xFFFF0000u);
}
__device__ __forceinline__ u32 pack_lo2(float a, float b) {
  float ra = a - __uint_as_float(__float_as_uint(a) & 0xFFFF0000u);
  float rb = b - __uint_as_float(__float_as_uint(b) & 0xFFFF0000u);
  return (__float_as_uint(ra) >> 16) | (__float_as_uint(rb) & 0xFFFF0000u);
}

// stage 16 consecutive fp32 into LDS as 16 hi-bf16 + 16 lo-bf16 (k3).
__device__ __forceinline__ void stage16(const float* __restrict__ p,
                                        u16* dhi, u16* dlo) {
  float4 a0 = *(const float4*)p;
  float4 a1 = *(const float4*)(p + 4);
  float4 a2 = *(const float4*)(p + 8);
  float4 a3 = *(const float4*)(p + 12);
  uint4 h0 = {pack_hi2(a0.x, a0.y), pack_hi2(a0.z, a0.w),
              pack_hi2(a1.x, a1.y), pack_hi2(a1.z, a1.w)};
  uint4 h1 = {pack_hi2(a2.x, a2.y), pack_hi2(a2.z, a2.w),
              pack_hi2(a3.x, a3.y), pack_hi2(a3.z, a3.w)};
  uint4 l0 = {pack_lo2(a0.x, a0.y), pack_lo2(a0.z, a0.w),
              pack_lo2(a1.x, a1.y), pack_lo2(a1.z, a1.w)};
  uint4 l1 = {pack_lo2(a2.x, a2.y), pack_lo2(a2.z, a2.w),
              pack_lo2(a3.x, a3.y), pack_lo2(a3.z, a3.w)};
  *(uint4*)dhi = h0;
  *(uint4*)(dhi + 8) = h1;
  *(uint4*)dlo = l0;
  *(uint4*)(dlo + 8) = l1;
}

// ---------------------------------------------------------------------------
// k_prep: merged scratch builder, grid (b, 9).
//  y<8 : cTh[b][i][h] = bf16_hi(ctx[b][h][i])  (128-i chunk per block)
//  y==8: qw[b][j][h] hi+lo (q*w_cq folded, aux row 128 = w_c, rows 129..143=0)
// ---------------------------------------------------------------------------
__global__ __launch_bounds__(256) void k_prep(
    const float* __restrict__ ctx, const float* __restrict__ qst,
    const float* __restrict__ w, u16* __restrict__ cTh,
    u16* __restrict__ qwh, u16* __restrict__ qwl) {
  const int b = blockIdx.x;
  const int y = blockIdx.y;
  const int tid = threadIdx.x;
  __shared__ float ld[128 * 129];
  __shared__ float wcq[128];

  if (y < 8) {
    const int i0 = y * 128;
    const float* cb = ctx + (size_t)b * HH * CC;
#pragma unroll
    for (int rep = 0; rep < 16; ++rep) {
      int h = rep * 8 + (tid >> 5);
      int io = (tid & 31) * 4;
      float4 v = *(const float4*)(cb + (size_t)h * CC + i0 + io);
      float* d = &ld[h * 129 + io];
      d[0] = v.x; d[1] = v.y; d[2] = v.z; d[3] = v.w;
    }
    __syncthreads();
    const int i = tid >> 1;
    const int hh0 = (tid & 1) * 64;
    u16* oh = cTh + (size_t)b * CC * HH + (size_t)(i0 + i) * 128 + hh0;
#pragma unroll
    for (int g = 0; g < 8; ++g) {
      u32 hw[4];
#pragma unroll
      for (int p = 0; p < 4; ++p) {
        int h = hh0 + g * 8 + p * 2;
        hw[p] = pack_hi2(ld[h * 129 + i], ld[(h + 1) * 129 + i]);
      }
      uint4 vh = {hw[0], hw[1], hw[2], hw[3]};
      *(uint4*)(oh + g * 8) = vh;
    }
  } else {
    const float* qb = qst + (size_t)b * HH * QQ;
#pragma unroll
    for (int rep = 0; rep < 16; ++rep) {
      int h = rep * 8 + (tid >> 5);
      int jo = (tid & 31) * 4;
      float4 v = *(const float4*)(qb + (size_t)h * QQ + jo);
      float* d = &ld[h * 129 + jo];
      d[0] = v.x; d[1] = v.y; d[2] = v.z; d[3] = v.w;
    }
    if (tid < 128) wcq[tid] = w[2 * HH + tid];
    __syncthreads();
    const int j = tid >> 1;
    const int hh0 = (tid & 1) * 64;
    u16* oh = qwh + (size_t)b * 144 * 128 + j * 128 + hh0;
    u16* ol = qwl + (size_t)b * 144 * 128 + j * 128 + hh0;
#pragma unroll
    for (int g = 0; g < 8; ++g) {
      u32 hw[4], lw[4];
#pragma unroll
      for (int p = 0; p < 4; ++p) {
        int h = hh0 + g * 8 + p * 2;
        float a = ld[h * 129 + j] * wcq[h];
        float c = ld[(h + 1) * 129 + j] * wcq[h + 1];
        hw[p] = pack_hi2(a, c);
        lw[p] = pack_lo2(a, c);
      }
      uint4 vh = {hw[0], hw[1], hw[2], hw[3]};
      uint4 vl = {lw[0], lw[1], lw[2], lw[3]};
      *(uint4*)(oh + g * 8) = vh;
      *(uint4*)(ol + g * 8) = vl;
    }
    // aux rows 128..143
    if (tid < 128) {
      int jr = 128 + (tid >> 3);
      int hc = (tid & 7) * 16;
      u32 hw[8], lw[8];
#pragma unroll
      for (int p = 0; p < 8; ++p) { hw[p] = 0; lw[p] = 0; }
      if (jr == 128) {
#pragma unroll
        for (int p = 0; p < 8; ++p) {
          float a = w[HH + hc + p * 2];
          float c = w[HH + hc + p * 2 + 1];
          hw[p] = pack_hi2(a, c);
          lw[p] = pack_lo2(a, c);
        }
      }
      u16* ph = qwh + (size_t)b * 144 * 128 + (size_t)jr * 128 + hc;
      u16* pl = qwl + (size_t)b * 144 * 128 + (size_t)jr * 128 + hc;
      uint4 vh0 = {hw[0], hw[1], hw[2], hw[3]};
      uint4 vh1 = {hw[4], hw[5], hw[6], hw[7]};
      uint4 vl0 = {lw[0], lw[1], lw[2], lw[3]};
      uint4 vl1 = {lw[4], lw[5], lw[6], lw[7]};
      *(uint4*)ph = vh0; *(uint4*)(ph + 8) = vh1;
      *(uint4*)pl = vl0; *(uint4*)(pl + 8) = vl1;
    }
  }
}

// ---------------------------------------------------------------------------
// k0_fused: per (b, 16-j tile):
//  phase 1 (r4-validated): s = qw @ cT^T via MFMA (+aux row -> cwc), softmax
//           over i in registers, write s1tb (k3 layout) + s1 tile into LDS.
//  phase 2 (absorbs old k2): t[j,h] = sum_i s1[i,j] c[i,h] via MFMA with
//           A = s1 LDS frags (free=j, K=i), B = ctx rows DIRECT from global
//           (free=h, K=i -- row-major ctx is already [h][i], no transpose).
//           Wave wv owns h-tile wv*16; full K=1024 per wave, no reduction.
// Eliminates s1ws buffer + the whole k2 kernel.
// ---------------------------------------------------------------------------
__global__ __launch_bounds__(512) void k0_fused(
    const float* __restrict__ ctx, const u16* __restrict__ cTh,
    const u16* __restrict__ qwh, const u16* __restrict__ qwl,
    u16* __restrict__ s1tb, float* __restrict__ tT) {
  const int b = blockIdx.x;
  const int j0 = blockIdx.y * 16;
  const int tid = threadIdx.x;
  const int lane = tid & 63;
  const int wv = tid >> 6;
  const int l15 = lane & 15, l4 = lane >> 4;
  __shared__ float wred[2][8][4][4];
  __shared__ u16 s1l[16 * 1026];   // pitch 1026: 513 dw % 32 = 1 -> 2-way max

  const u16* cb = cTh + (size_t)b * CC * HH;
  const u16* qhp = qwh + (size_t)b * 144 * 128;
  const u16* qlp = qwl + (size_t)b * 144 * 128;

  // A-frag cache (loop-invariant): real j-tile hi+lo, aux tile hi.
  bf16x8 aqh[4], aql[4], axh[4];
#pragma unroll
  for (int kk = 0; kk < 4; ++kk) {
    const int off = kk * 32 + l4 * 8;
    aqh[kk] = *(const bf16x8*)(qhp + (size_t)(j0 + l15) * 128 + off);
    aql[kk] = *(const bf16x8*)(qlp + (size_t)(j0 + l15) * 128 + off);
    axh[kk] = *(const bf16x8*)(qhp + (size_t)(128 + l15) * 128 + off);
  }

  f32x4 sv[8];
  float cwcv[8];
#pragma unroll
  for (int it = 0; it < 8; ++it) {
    const int i = wv * 128 + it * 16 + l15;
    f32x4 aR = {0.f, 0.f, 0.f, 0.f};
    f32x4 aX = {0.f, 0.f, 0.f, 0.f};
#pragma unroll
    for (int kk = 0; kk < 4; ++kk) {
      bf16x8 bh = *(const bf16x8*)(cb + (size_t)i * 128 + kk * 32 + l4 * 8);
      aR = MFMA16(aqh[kk], bh, aR);
      aR = MFMA16(aql[kk], bh, aR);
      aX = MFMA16(axh[kk], bh, aX);
    }
    cwcv[it] = __shfl(aX[0], l15);   // aux D row 0 = cwc[i]
    sv[it] = aR;
  }
#pragma unroll
  for (int it = 0; it < 8; ++it)
#pragma unroll
    for (int r = 0; r < 4; ++r) sv[it][r] += cwcv[it];

  // ---- max over i, per j = j0 + l4*4 + r ----
  float mj[4];
#pragma unroll
  for (int r = 0; r < 4; ++r) {
    float m = sv[0][r];
#pragma unroll
    for (int it = 1; it < 8; ++it) m = fmaxf(m, sv[it][r]);
#pragma unroll
    for (int msk = 1; msk < 16; msk <<= 1) m = fmaxf(m, __shfl_xor(m, msk));
    mj[r] = m;
  }
  if (l15 == 0) {
#pragma unroll
    for (int r = 0; r < 4; ++r) wred[0][wv][l4][r] = mj[r];
  }
  __syncthreads();
  float gm[4];
#pragma unroll
  for (int r = 0; r < 4; ++r) {
    float m = wred[0][0][l4][r];
#pragma unroll
    for (int w2 = 1; w2 < 8; ++w2) m = fmaxf(m, wred[0][w2][l4][r]);
    gm[r] = m;
  }

  // ---- exp + sum ----
#pragma unroll
  for (int it = 0; it < 8; ++it)
#pragma unroll
    for (int r = 0; r < 4; ++r) sv[it][r] = __expf(sv[it][r] - gm[r]);
  float sj[4];
#pragma unroll
  for (int r = 0; r < 4; ++r) {
    float s = 0.f;
#pragma unroll
    for (int it = 0; it < 8; ++it) s += sv[it][r];
#pragma unroll
    for (int msk = 1; msk < 16; msk <<= 1) s += __shfl_xor(s, msk);
    sj[r] = s;
  }
  if (l15 == 0) {
#pragma unroll
    for (int r = 0; r < 4; ++r) wred[1][wv][l4][r] = sj[r];
  }
  __syncthreads();
  float inv_[4];
#pragma unroll
  for (int r = 0; r < 4; ++r) {
    float s = 0.f;
#pragma unroll
    for (int w2 = 0; w2 < 8; ++w2) s += wred[1][w2][l4][r];
    inv_[r] = 1.0f / s;
  }

  // ---- write s1tb (k3 layout) + s1 LDS tile ----
  u16* tb = s1tb + (size_t)b * (16 * 1024 * 8);
#pragma unroll
  for (int it = 0; it < 8; ++it) {
    const int i = wv * 128 + it * 16 + l15;
#pragma unroll
    for (int r = 0; r < 4; ++r) {
      const int j = j0 + l4 * 4 + r;
      u16 pv = f2b(sv[it][r] * inv_[r]);
      tb[((size_t)(j >> 3) * 1024 + i) * 8 + (j & 7)] = pv;
      s1l[(l4 * 4 + r) * 1026 + i] = pv;
    }
  }
  __syncthreads();

  // ---- phase 2: t[j, h] for this j-tile, wave wv owns h = wv*16 + l15 ----
  const float* cxr = ctx + ((size_t)b * HH + wv * 16 + l15) * CC;
  f32x4 tacc = {0.f, 0.f, 0.f, 0.f};
#pragma unroll 4
  for (int kk = 0; kk < 32; ++kk) {
    const int ib = kk * 32 + l4 * 8;
    float4 c0 = *(const float4*)(cxr + ib);
    float4 c1 = *(const float4*)(cxr + ib + 4);
    uint4 hb = {pack_hi2(c0.x, c0.y), pack_hi2(c0.z, c0.w),
                pack_hi2(c1.x, c1.y), pack_hi2(c1.z, c1.w)};
    uint4 lb = {pack_lo2(c0.x, c0.y), pack_lo2(c0.z, c0.w),
                pack_lo2(c1.x, c1.y), pack_lo2(c1.z, c1.w)};
    bf16x8 af = *(const bf16x8*)&s1l[l15 * 1026 + ib];
    tacc = MFMA16(af, *(const bf16x8*)&hb, tacc);
    tacc = MFMA16(af, *(const bf16x8*)&lb, tacc);
  }
  // D: row (l4*4+r) = j-local, col (l15) = h-local.  tT[b][h][j].
  float* tw = tT + (size_t)b * HH * QQ + (size_t)(wv * 16 + l15) * QQ + j0;
#pragma unroll
  for (int r = 0; r < 4; ++r) tw[l4 * 4 + r] = tacc[r];
}

// ---------------------------------------------------------------------------
// K3 (MFMA): a[i,h] = sum_j s1[i,j] q[j,h];  bb[i,h] = sum_j s1[i,j] t[j,h]
// ---------------------------------------------------------------------------
__global__ __launch_bounds__(256, 2) void k3_out(
    const float* __restrict__ ctx, const float* __restrict__ qst,
    const u16* __restrict__ s1tb, const float* __restrict__ tT,
    float* __restrict__ out) {
  const int b = blockIdx.x;
  const int i0 = blockIdx.y * 128;
  const int tid = threadIdx.x;
  const int lane = tid & 63;
  const int wv = tid >> 6;
  const int l15 = lane & 15, l4 = lane >> 4;

  __shared__ u16 qHi[128 * 40], qLo[128 * 40];
  __shared__ u16 tHi[128 * 40], tLo[128 * 40];

  f32x4 accA[8][2], accB[8][2];
#pragma unroll
  for (int it = 0; it < 8; ++it)
#pragma unroll
    for (int ht = 0; ht < 2; ++ht) { accA[it][ht] = 0.f; accB[it][ht] = 0.f; }

  const u16* stb = s1tb + (size_t)b * (16 * 1024 * 8);
  const float* qb = qst + (size_t)b * HH * QQ;
  const float* tb = tT + (size_t)b * HH * QQ;
  const int srow = tid >> 1;
  const int scol = (tid & 1) * 16;

  for (int ks = 0; ks < 4; ++ks) {
    const int jb = ks * 32;
    __syncthreads();
    stage16(qb + (size_t)srow * QQ + jb + scol,
            &qHi[srow * 40 + scol], &qLo[srow * 40 + scol]);
    stage16(tb + (size_t)srow * QQ + jb + scol,
            &tHi[srow * 40 + scol], &tLo[srow * 40 + scol]);
    __syncthreads();
    bf16x8 qh[2], ql[2], th[2], tl[2];
#pragma unroll
    for (int ht = 0; ht < 2; ++ht) {
      const int ar = (wv * 32 + ht * 16 + l15) * 40 + l4 * 8;
      qh[ht] = *(const bf16x8*)&qHi[ar];
      ql[ht] = *(const bf16x8*)&qLo[ar];
      th[ht] = *(const bf16x8*)&tHi[ar];
      tl[ht] = *(const bf16x8*)&tLo[ar];
    }
#pragma unroll
    for (int half = 0; half < 2; ++half) {
      bf16x8 bfr[4];
#pragma unroll
      for (int t4 = 0; t4 < 4; ++t4) {
        const int it = half * 4 + t4;
        bfr[t4] = *(const bf16x8*)(stb +
            ((size_t)(ks * 4 + l4) * 1024 + i0 + it * 16 + l15) * 8);
      }
#pragma unroll
      for (int t4 = 0; t4 < 4; ++t4) {
        const int it = half * 4 + t4;
#pragma unroll
        for (int ht = 0; ht < 2; ++ht) {
          accA[it][ht] = MFMA16(qh[ht], bfr[t4], accA[it][ht]);
          accA[it][ht] = MFMA16(ql[ht], bfr[t4], accA[it][ht]);
          accB[it][ht] = MFMA16(th[ht], bfr[t4], accB[it][ht]);
          accB[it][ht] = MFMA16(tl[ht], bfr[t4], accB[it][ht]);
        }
      }
    }
  }

  const float* cb = ctx + (size_t)b * HH * CC;
  float* ob = out + (size_t)b * 4 * HH * CC;
#pragma unroll
  for (int it = 0; it < 8; ++it) {
    const int ii = i0 + it * 16 + l15;
#pragma unroll
    for (int ht = 0; ht < 2; ++ht) {
#pragma unroll
      for (int r = 0; r < 4; ++r) {
        const int h = wv * 32 + ht * 16 + l4 * 4 + r;
        const size_t base = (size_t)h * CC + ii;
        const float cv = cb[base];
        const float av = accA[it][ht][r];
        const float bv = accB[it][ht][r];
        ob[base] = cv;
        ob[(size_t)HH * CC + base] = av;
        ob[(size_t)2 * HH * CC + base] = cv * av;
        ob[(size_t)3 * HH * CC + base] = cv * bv;
      }
    }
  }
}

extern "C" void kernel_launch(void* const* d_in, const int* in_sizes, int n_in,
                              void* d_out, int out_size, void* d_ws, size_t ws_size,
                              hipStream_t stream) {
  const float* ctx = (const float*)d_in[0];
  const float* qst = (const float*)d_in[1];
  const float* w = (const float*)d_in[2];
  for (int k = 0; k < n_in; ++k) {
    if (in_sizes[k] == BB * HH * CC) ctx = (const float*)d_in[k];
    else if (in_sizes[k] == BB * HH * QQ) qst = (const float*)d_in[k];
    else if (in_sizes[k] == 3 * HH) w = (const float*)d_in[k];
  }
  float* out = (float*)d_out;

  // Workspace: s1tb bf16 (16 MiB) + tT fp32 (4 MiB).  (s1ws eliminated.)
  u16* s1tb = (u16*)d_ws;
  float* tT = (float*)((char*)d_ws + (size_t)16 * 1024 * 1024);

  // Scratch for qw/cT in the TAIL of out (dead until k3 overwrites all of
  // out; written before read each launch).  Offsets 16B-aligned.
  char* ob = (char*)d_out;
  u16* qwl = (u16*)(ob + 112721920);   // 2,359,296 B
  u16* qwh = (u16*)(ob + 115081216);   // 2,359,296 B
  u16* cTh = (u16*)(ob + 117440512);   // 16,777,216 B -> ends at 134,217,728

  k_prep<<<dim3(BB, 9), 256, 0, stream>>>(ctx, qst, w, cTh, qwh, qwl);
  k0_fused<<<dim3(BB, 8), 512, 0, stream>>>(ctx, cTh, qwh, qwl, s1tb, tT);
  k3_out<<<dim3(BB, 8), 256, 0, stream>>>(ctx, qst, s1tb, tT, out);
}